// Round 4
// baseline (91.668 us; speedup 1.0000x reference)
//
#include <hip/hip_runtime.h>
#include <hip/hip_bf16.h>
#include <math.h>

#define NB      64      // batch
#define NNODES  1023    // 2*512-1
#define LC      20      // L*C = 5*4
#define DIN     512
#define NROWS   (NB * NNODES)   // 65472 = 1023 * 64 exactly
#define ET_PAD  404     // 400 + 4 pad

#define TRG     64              // rows per block
#define BLK     512             // threads per block (8 waves)
#define KC      32              // k per chunk
#define KP      36              // padded k stride: (lane + k4) % 8 quad spread
#define NCH     (DIN / KC)      // 16 chunks

// ---------------------------------------------------------------------------
// prep: ET[q][i*20+j] = exp(trans[...]) reindexed; Wt[q][k] = W[k][q]
// ---------------------------------------------------------------------------
__global__ __launch_bounds__(256) void prep_kernel(
    const float* __restrict__ trans, const float* __restrict__ W,
    float* __restrict__ ET, float* __restrict__ Wt)
{
    int t = blockIdx.x * 256 + threadIdx.x;
    if (t < 8000) {
        int q   = t % 20;
        int rem = t / 20;
        int j   = rem % 20;
        int i   = rem / 20;
        int ll = i >> 2, cl = i & 3;
        int lr = j >> 2, cr = j & 3;
        int lp = q >> 2, cp = q & 3;
        int src = ((((lp * 5 + ll) * 5 + lr) * 4 + cp) * 4 + cl) * 4 + cr;
        ET[q * ET_PAD + i * 20 + j] = expf(trans[src]);
    }
    if (t < LC * DIN) {
        int q = t / DIN;
        int k = t - q * DIN;
        Wt[t] = W[k * LC + q];
    }
}

// ---------------------------------------------------------------------------
// gemm: buf[row][q] = dot(h[row,:], W[:,q]) + b[q]
// 8 waves/block, 64-row LDS tile. wave w: q-group (w>>1)*5, k-half (w&1)*16.
// Wt slices are wave-uniform -> scalar loads. LDS b128 conflict-free (KP=36).
// ---------------------------------------------------------------------------
__global__ __launch_bounds__(BLK) void gemm_kernel(
    const float* __restrict__ h, const float* __restrict__ Wt,
    const float* __restrict__ bias, float* __restrict__ buf)
{
    __shared__ float As[2][TRG][KP];
    const int t    = threadIdx.x;
    const int lane = t & 63;
    const int wv   = t >> 6;
    const int w5   = __builtin_amdgcn_readfirstlane((wv >> 1) * 5);
    const int kh16 = __builtin_amdgcn_readfirstlane((wv & 1) * 16);
    const int row0 = blockIdx.x * TRG;

    const int srr = t >> 3, sk4 = t & 7;  // staging: row, float4-slot
    const float* hsrc = h + (size_t)(row0 + srr) * DIN + sk4 * 4;

    float acc[5] = {0.f, 0.f, 0.f, 0.f, 0.f};

    // stage chunk 0 (one float4 per thread)
    *(float4*)&As[0][srr][sk4 * 4] = *(const float4*)hsrc;
    __syncthreads();

    for (int c = 0; c < NCH; ++c) {
        const int cur = c & 1;
        const bool more = (c + 1 < NCH);
        float4 nxt;
        if (more) nxt = *(const float4*)(hsrc + (c + 1) * KC);

        const int kb = c * KC + kh16;
        #pragma unroll
        for (int k4 = 0; k4 < 4; ++k4) {
            float4 a = *(const float4*)&As[cur][lane][kh16 + k4 * 4];
            const float* wr = Wt + (size_t)w5 * DIN + kb + k4 * 4;
            #pragma unroll
            for (int j = 0; j < 5; ++j) {
                const float* wj = wr + j * DIN;
                acc[j] = fmaf(a.x, wj[0], acc[j]);
                acc[j] = fmaf(a.y, wj[1], acc[j]);
                acc[j] = fmaf(a.z, wj[2], acc[j]);
                acc[j] = fmaf(a.w, wj[3], acc[j]);
            }
        }

        if (more) *(float4*)&As[cur ^ 1][srr][sk4 * 4] = nxt;
        __syncthreads();
    }

    // epilogue: combine k-halves + bias, transpose via LDS scratch, coalesced
    float* r0 = (float*)As;          // [64][20] partials, k-half 0
    float* r1 = r0 + TRG * LC;       // [64][20] partials, k-half 1
    float* reg = (wv & 1) ? r1 : r0;
    #pragma unroll
    for (int j = 0; j < 5; ++j)
        reg[lane * LC + w5 + j] = acc[j];
    __syncthreads();
    if (t < TRG * LC / 4) {
        float4 p0 = ((const float4*)r0)[t];
        float4 p1 = ((const float4*)r1)[t];
        float4 bv = ((const float4*)bias)[t % 5];
        float4 o  = make_float4(p0.x + p1.x + bv.x, p0.y + p1.y + bv.y,
                                p0.z + p1.z + bv.z, p0.w + p1.w + bv.w);
        ((float4*)(buf + (size_t)row0 * LC))[t] = o;
    }
}

// ---------------------------------------------------------------------------
// level body (shared by level_kernel and tail_kernel)
// ---------------------------------------------------------------------------
__device__ __forceinline__ void level_body(
    float* __restrict__ buf, const float* __restrict__ et,
    float* __restrict__ out, int bi, int node, int q)
{
    size_t pbase = ((size_t)bi * NNODES + node) * LC;
    size_t lbase = ((size_t)bi * NNODES + 2 * node + 1) * LC;

    float l[LC], r[LC];
    const float4* l4 = (const float4*)(buf + lbase);
    const float4* r4 = (const float4*)(buf + lbase + LC);
    #pragma unroll
    for (int v = 0; v < 5; ++v) {
        float4 lv = l4[v], rv = r4[v];
        l[4*v+0] = lv.x; l[4*v+1] = lv.y; l[4*v+2] = lv.z; l[4*v+3] = lv.w;
        r[4*v+0] = rv.x; r[4*v+1] = rv.y; r[4*v+2] = rv.z; r[4*v+3] = rv.w;
    }
    float maxl = l[0], maxr = r[0];
    #pragma unroll
    for (int i = 1; i < LC; ++i) {
        maxl = fmaxf(maxl, l[i]);
        maxr = fmaxf(maxr, r[i]);
    }
    float el[LC], er[LC];
    #pragma unroll
    for (int i = 0; i < LC; ++i) {
        el[i] = __expf(l[i] - maxl);
        er[i] = __expf(r[i] - maxr);
    }

    const float4* etq = (const float4*)(et + q * ET_PAD);
    float s = 0.f;
    #pragma unroll
    for (int i = 0; i < LC; ++i) {
        float4 e0 = etq[i*5+0], e1 = etq[i*5+1], e2 = etq[i*5+2],
               e3 = etq[i*5+3], e4 = etq[i*5+4];
        float d0 = 0.f, d1 = 0.f;
        d0 = fmaf(e0.x, er[0],  d0); d1 = fmaf(e0.y, er[1],  d1);
        d0 = fmaf(e0.z, er[2],  d0); d1 = fmaf(e0.w, er[3],  d1);
        d0 = fmaf(e1.x, er[4],  d0); d1 = fmaf(e1.y, er[5],  d1);
        d0 = fmaf(e1.z, er[6],  d0); d1 = fmaf(e1.w, er[7],  d1);
        d0 = fmaf(e2.x, er[8],  d0); d1 = fmaf(e2.y, er[9],  d1);
        d0 = fmaf(e2.z, er[10], d0); d1 = fmaf(e2.w, er[11], d1);
        d0 = fmaf(e3.x, er[12], d0); d1 = fmaf(e3.y, er[13], d1);
        d0 = fmaf(e3.z, er[14], d0); d1 = fmaf(e3.w, er[15], d1);
        d0 = fmaf(e4.x, er[16], d0); d1 = fmaf(e4.y, er[17], d1);
        d0 = fmaf(e4.z, er[18], d0); d1 = fmaf(e4.w, er[19], d1);
        s = fmaf(el[i], d0 + d1, s);
    }

    float val = buf[pbase + q] + maxl + maxr + __logf(s);
    buf[pbase + q] = val;
    if (out) out[(size_t)bi * LC + q] = val;
}

// ---------------------------------------------------------------------------
// level: one launch per level for d = 8, 7, 6
// ---------------------------------------------------------------------------
__global__ __launch_bounds__(256) void level_kernel(
    float* __restrict__ buf, const float* __restrict__ ETg,
    int start, int count)
{
    __shared__ float et[LC * ET_PAD];
    for (int idx = threadIdx.x; idx < LC * ET_PAD / 4; idx += 256)
        ((float4*)et)[idx] = ((const float4*)ETg)[idx];
    __syncthreads();

    int t  = blockIdx.x * 256 + threadIdx.x;
    int pj = t / LC;
    int q  = t - pj * LC;
    if (pj >= NB * count) return;
    int bi   = pj / count;
    int node = start + (pj - bi * count);
    level_body(buf, et, nullptr, bi, node, q);
}

// ---------------------------------------------------------------------------
// tail: levels d = 5..0 fused, one block per batch element
// ---------------------------------------------------------------------------
__global__ __launch_bounds__(640) void tail_kernel(
    float* __restrict__ buf, const float* __restrict__ ETg,
    float* __restrict__ out)
{
    __shared__ float et[LC * ET_PAD];
    for (int idx = threadIdx.x; idx < LC * ET_PAD / 4; idx += 640)
        ((float4*)et)[idx] = ((const float4*)ETg)[idx];
    __syncthreads();

    const int bi = blockIdx.x;
    for (int d = 5; d >= 0; --d) {
        int count = 1 << d;
        int start = count - 1;
        int t = threadIdx.x;
        if (t < count * LC) {
            int node = start + t / LC;
            int q    = t % LC;
            level_body(buf, et, (d == 0) ? out : nullptr, bi, node, q);
        }
        __syncthreads();
    }
}

// ---------------------------------------------------------------------------
extern "C" void kernel_launch(void* const* d_in, const int* in_sizes, int n_in,
                              void* d_out, int out_size, void* d_ws, size_t ws_size,
                              hipStream_t stream)
{
    const float* h     = (const float*)d_in[0];
    const float* W     = (const float*)d_in[1];
    const float* bias  = (const float*)d_in[2];
    const float* trans = (const float*)d_in[3];

    char* ws = (char*)d_ws;
    float* ET  = (float*)(ws);                       // 32320 B (pad to 32768)
    float* Wt  = (float*)(ws + 32768);               // 20*512*4 = 40960 B
    float* buf = (float*)(ws + 32768 + 40960);       // 65472*20*4 B

    // 1. precompute exp(trans) reindexed + W^T
    prep_kernel<<<(LC * DIN + 255) / 256, 256, 0, stream>>>(trans, W, ET, Wt);

    // 2. sw = h@W + b
    gemm_kernel<<<NROWS / TRG, BLK, 0, stream>>>(h, Wt, bias, buf);

    // 3. inside pass: big levels separate, small levels fused
    for (int d = 8; d >= 6; --d) {
        int count = 1 << d;
        int start = count - 1;
        int T = NB * count * LC;
        level_kernel<<<(T + 255) / 256, 256, 0, stream>>>(buf, ET, start, count);
    }
    tail_kernel<<<NB, 640, 0, stream>>>(buf, ET, (float*)d_out);
}